// Round 1
// baseline (4359.343 us; speedup 1.0000x reference)
//
#include <hip/hip_runtime.h>
#include <stdint.h>

#pragma clang fp contract(off)

#define N_ANCH 262144
#define BATCH 8
#define TOPK 5000
#define PROP 1000
#define SORTN 8192
#define NEGF -1000000000.0f
#define MAXR 4.135166556742356f

__device__ __forceinline__ unsigned ord32(float f){
  unsigned u = __float_as_uint(f);
  return (u & 0x80000000u) ? ~u : (u | 0x80000000u);
}
__device__ __forceinline__ float unord32(unsigned o){
  unsigned u = (o & 0x80000000u) ? (o & 0x7FFFFFFFu) : ~o;
  return __uint_as_float(u);
}

// masked score for (b, i)
__device__ __forceinline__ float masked_score(const float* __restrict__ score,
                                              const float4* __restrict__ anchors,
                                              int b, int i){
  float4 a = anchors[i];
  bool valid = (a.z <= 1.0f) && (a.w <= 1.0f) && (a.x >= 0.0f) && (a.y >= 0.0f);
  float s = score[(size_t)b*N_ANCH + i];
  return valid ? s : -1.0f;
}

// Pass 1: histogram of top-16 bits of ordered score (only s >= 0.5; ~92K/batch, far above 5000)
__global__ void k_hist1(const float* __restrict__ score, const float4* __restrict__ anchors,
                        unsigned* __restrict__ hist){
  int b = blockIdx.y;
  int i = blockIdx.x*blockDim.x + threadIdx.x;
  float s = masked_score(score, anchors, b, i);
  unsigned o = ord32(s);
  if (o >= 0xBF000000u)  // s >= 0.5
    atomicAdd(&hist[(size_t)b*65536u + (o>>16)], 1u);
}

// Find 16-bit bucket containing rank-5000 (from top); store bucket + strict-above count
__global__ void k_find1(const unsigned* __restrict__ hist, unsigned* __restrict__ meta){
  int b = blockIdx.x; int t = threadIdx.x;
  __shared__ unsigned part[256];
  const unsigned* h = hist + (size_t)b*65536u;
  unsigned sum = 0;
  for (int k=0;k<256;++k) sum += h[t*256+k];
  part[t]=sum; __syncthreads();
  if (t==0){
    unsigned cum=0; int tr=0;
    for (int q=255;q>=0;--q){ if (cum + part[q] >= TOPK){ tr=q; break;} cum += part[q]; }
    unsigned b1 = tr*256; unsigned cA = cum;
    for (int bin=tr*256+255; bin>=tr*256; --bin){
      unsigned hh = h[bin];
      if (cA + hh >= TOPK){ b1 = (unsigned)bin; break; }
      cA += hh;
    }
    meta[b*8+0]=b1; meta[b*8+1]=cA;
  }
}

// Pass 2: refine low 16 bits within the threshold bucket
__global__ void k_hist2(const float* __restrict__ score, const float4* __restrict__ anchors,
                        const unsigned* __restrict__ meta, unsigned* __restrict__ hist){
  int b = blockIdx.y;
  int i = blockIdx.x*blockDim.x + threadIdx.x;
  float s = masked_score(score, anchors, b, i);
  unsigned o = ord32(s);
  unsigned b1 = meta[b*8+0];
  if ((o>>16) == b1)
    atomicAdd(&hist[(size_t)b*65536u + (o & 0xFFFFu)], 1u);
}

__global__ void k_find2(const unsigned* __restrict__ hist, unsigned* __restrict__ meta){
  int b = blockIdx.x; int t = threadIdx.x;
  __shared__ unsigned part[256];
  const unsigned* h = hist + (size_t)b*65536u;
  unsigned sum=0;
  for (int k=0;k<256;++k) sum += h[t*256+k];
  part[t]=sum; __syncthreads();
  if (t==0){
    unsigned cum = meta[b*8+1];
    int tr=0;
    for (int q=255;q>=0;--q){ if (cum+part[q] >= TOPK){tr=q;break;} cum+=part[q]; }
    unsigned b2 = tr*256;
    for (int bin=tr*256+255; bin>=tr*256; --bin){
      unsigned hh=h[bin];
      if (cum+hh >= TOPK){ b2=(unsigned)bin; break; }
      cum+=hh;
    }
    meta[b*8+2] = (meta[b*8+0]<<16) | b2;  // exact 32-bit ordered-score threshold
  }
}

// Compact: strictly-above -> cand (key = ~ord<<32 | idx, sorts score desc / idx asc);
// equal-to-threshold -> candEq (indices)
__global__ void k_compact(const float* __restrict__ score, const float4* __restrict__ anchors,
                          unsigned* __restrict__ meta,
                          unsigned long long* __restrict__ cand, unsigned* __restrict__ candEq){
  int b = blockIdx.y;
  int i = blockIdx.x*blockDim.x + threadIdx.x;
  float s = masked_score(score, anchors, b, i);
  unsigned o = ord32(s);
  unsigned T = meta[b*8+2];
  if (o > T){
    unsigned pos = atomicAdd(&meta[b*8+3], 1u);
    if (pos < SORTN) cand[(size_t)b*SORTN + pos] = (((unsigned long long)(~o)) << 32) | (unsigned)i;
  } else if (o == T){
    unsigned pos = atomicAdd(&meta[b*8+4], 1u);
    if (pos < SORTN) candEq[(size_t)b*SORTN + pos] = (unsigned)i;
  }
}

// Bitonic-sort candidates (pad to 8192), emit first 5000 keys (stable top-k order)
__global__ void __launch_bounds__(1024) k_sort(const unsigned* __restrict__ meta,
                       const unsigned long long* __restrict__ cand,
                       const unsigned* __restrict__ candEq,
                       unsigned long long* __restrict__ sorted){
  __shared__ unsigned long long keys[SORTN];
  int b = blockIdx.x; int t = threadIdx.x;
  unsigned cntA = meta[b*8+3];
  unsigned cntEq = meta[b*8+4];
  if (cntA > (unsigned)SORTN) cntA = SORTN;
  if (cntEq > (unsigned)SORTN - cntA) cntEq = SORTN - cntA;
  unsigned tot = cntA + cntEq;
  unsigned T = meta[b*8+2];
  unsigned long long eqHi = ((unsigned long long)(~T)) << 32;
  for (unsigned j=t; j<SORTN; j+=1024u){
    unsigned long long k;
    if (j < cntA) k = cand[(size_t)b*SORTN + j];
    else if (j < tot) k = eqHi | candEq[(size_t)b*SORTN + (j - cntA)];
    else k = ~0ull;
    keys[j]=k;
  }
  __syncthreads();
  for (unsigned k=2;k<=SORTN;k<<=1){
    for (unsigned j=k>>1;j>0;j>>=1){
      for (unsigned i=t;i<SORTN;i+=1024u){
        unsigned l = i ^ j;
        if (l > i){
          unsigned long long a = keys[i], c = keys[l];
          bool up = ((i & k) == 0u);
          if ((a > c) == up){ keys[i]=c; keys[l]=a; }
        }
      }
      __syncthreads();
    }
  }
  for (unsigned j=t;j<TOPK;j+=1024u) sorted[(size_t)b*TOPK + j] = keys[j];
}

// Sequential soft-NMS, one block per batch, everything in LDS (~120 KB)
__global__ void __launch_bounds__(1024) k_nms(const unsigned long long* __restrict__ sorted,
                      const float4* __restrict__ anchors, const float4* __restrict__ regress,
                      float* __restrict__ out){
  __shared__ float bx[TOPK*4];
  __shared__ float ar[TOPK];
  __shared__ float sc[TOPK];
  __shared__ float rs[16];
  __shared__ int   ri[16];
  __shared__ int bestI;
  int b = blockIdx.x; int t = threadIdx.x;
  // gather + delta2bbox + clip + area
  for (int j=t;j<TOPK;j+=1024){
    unsigned long long key = sorted[(size_t)b*TOPK + j];
    unsigned o = ~(unsigned)(key>>32);
    unsigned idx = (unsigned)key;
    float s = unord32(o);
    float4 a = anchors[idx];
    float4 d = regress[(size_t)b*N_ANCH + idx];
    float dx = d.x*0.1f, dy = d.y*0.1f;
    float dw = d.z*0.2f, dh = d.w*0.2f;
    dw = fminf(fmaxf(dw, -MAXR), MAXR);
    dh = fminf(fmaxf(dh, -MAXR), MAXR);
    float aw = a.z - a.x, ah = a.w - a.y;
    float cx = (a.z + a.x)*0.5f, cy = (a.w + a.y)*0.5f;
    float ncx = cx + dx*aw, ncy = cy + dy*ah;
    float nw = aw*expf(dw), nh = ah*expf(dh);
    float x1 = ncx - nw*0.5f, y1 = ncy - nh*0.5f;
    float x2 = ncx + nw*0.5f, y2 = ncy + nh*0.5f;
    x1 = fminf(fmaxf(x1,0.f),1.f); y1 = fminf(fmaxf(y1,0.f),1.f);
    x2 = fminf(fmaxf(x2,0.f),1.f); y2 = fminf(fmaxf(y2,0.f),1.f);
    bx[j*4+0]=x1; bx[j*4+1]=y1; bx[j*4+2]=x2; bx[j*4+3]=y2;
    ar[j] = (x2-x1)*(y2-y1);
    sc[j] = s;
  }
  __syncthreads();
  int lane = t & 63, wid = t >> 6;
  for (int it=0; it<PROP; ++it){
    // argmax with first-occurrence (smallest position) tie-break
    float bs = -INFINITY; int bp = TOPK;
    for (int j=t;j<TOPK;j+=1024){
      float s = sc[j];
      if (s > bs){ bs = s; bp = j; }   // j increasing => smallest j kept on ties
    }
    for (int m=1;m<64;m<<=1){
      float s2 = __shfl_xor(bs, m);
      int   p2 = __shfl_xor(bp, m);
      if (s2 > bs || (s2 == bs && p2 < bp)){ bs = s2; bp = p2; }
    }
    if (lane==0){ rs[wid]=bs; ri[wid]=bp; }
    __syncthreads();
    if (t==0){
      float s = rs[0]; int p = ri[0];
      for (int w=1;w<16;++w){
        float s2 = rs[w]; int p2 = ri[w];
        if (s2 > s || (s2 == s && p2 < p)){ s = s2; p = p2; }
      }
      bestI = p;
      float4 bb;
      if (s > NEGF*0.5f){ bb = *(const float4*)&bx[p*4]; }
      else { bb = make_float4(0.f,0.f,0.f,0.f); }
      *(float4*)(out + ((size_t)b*PROP + it)*4) = bb;
    }
    __syncthreads();
    int i = bestI;
    float bx1 = bx[i*4+0], by1 = bx[i*4+1], bx2 = bx[i*4+2], by2 = bx[i*4+3];
    float ai = ar[i];
    for (int j=t;j<TOPK;j+=1024){
      if (j == i){ sc[j] = NEGF; continue; }
      float ltx = fmaxf(bx1, bx[j*4+0]);
      float lty = fmaxf(by1, bx[j*4+1]);
      float rbx = fminf(bx2, bx[j*4+2]);
      float rby = fminf(by2, bx[j*4+3]);
      float iw = fmaxf(rbx-ltx, 0.f);
      float ih = fmaxf(rby-lty, 0.f);
      float inter = iw*ih;
      float iou = inter/(ai + ar[j] - inter + 1e-12f);
      sc[j] = sc[j]*expf(-(iou*iou));  // == exp(-0.5*iou*iou/0.5) bitwise
    }
    __syncthreads();
  }
}

extern "C" void kernel_launch(void* const* d_in, const int* in_sizes, int n_in,
                              void* d_out, int out_size, void* d_ws, size_t ws_size,
                              hipStream_t stream){
  const float*  score   = (const float*) d_in[0];
  const float4* regress = (const float4*)d_in[1];
  const float4* anchors = (const float4*)d_in[2];
  float* out = (float*)d_out;
  char* ws = (char*)d_ws;
  // ws layout
  unsigned* hist = (unsigned*)(ws + 0);                                   // 8*65536*4 = 2 MB (reused)
  unsigned* meta = (unsigned*)(ws + 2097152);                             // 8*8*4 = 256 B
  unsigned long long* cand   = (unsigned long long*)(ws + 2097152 + 1024);            // 8*8192*8 = 512 KB
  unsigned* candEq           = (unsigned*)(ws + 2097152 + 1024 + 524288);             // 8*8192*4 = 256 KB
  unsigned long long* sorted = (unsigned long long*)(ws + 2097152 + 1024 + 524288 + 262144); // 8*5000*8

  hipMemsetAsync(ws, 0, 2097152 + 1024, stream);  // hist + meta (incl. atomic counters)
  dim3 g1(N_ANCH/256, BATCH);
  k_hist1<<<g1, 256, 0, stream>>>(score, anchors, hist);
  k_find1<<<BATCH, 256, 0, stream>>>(hist, meta);
  hipMemsetAsync(hist, 0, 2097152, stream);
  k_hist2<<<g1, 256, 0, stream>>>(score, anchors, meta, hist);
  k_find2<<<BATCH, 256, 0, stream>>>(hist, meta);
  k_compact<<<g1, 256, 0, stream>>>(score, anchors, meta, cand, candEq);
  k_sort<<<BATCH, 1024, 0, stream>>>(meta, cand, candEq, sorted);
  k_nms<<<BATCH, 1024, 0, stream>>>(sorted, anchors, regress, out);
}

// Round 7
// 2923.718 us; speedup vs baseline: 1.4910x; 1.4910x over previous
//
#include <hip/hip_runtime.h>
#include <stdint.h>

#pragma clang fp contract(off)

#define N_ANCH 262144
#define BATCH 8
#define TOPK 5000
#define PROP 1000
#define SORTN 8192
#define NEGF -1000000000.0f
#define MAXR 4.135166556742356f
#define NMS_T 512
#define NMS_K 10

__device__ __forceinline__ unsigned ord32(float f){
  unsigned u = __float_as_uint(f);
  return (u & 0x80000000u) ? ~u : (u | 0x80000000u);
}
__device__ __forceinline__ float unord32(unsigned o){
  unsigned u = (o & 0x80000000u) ? (o & 0x7FFFFFFFu) : ~o;
  return __uint_as_float(u);
}

// masked score for (b, i)
__device__ __forceinline__ float masked_score(const float* __restrict__ score,
                                              const float4* __restrict__ anchors,
                                              int b, int i){
  float4 a = anchors[i];
  bool valid = (a.z <= 1.0f) && (a.w <= 1.0f) && (a.x >= 0.0f) && (a.y >= 0.0f);
  float s = score[(size_t)b*N_ANCH + i];
  return valid ? s : -1.0f;
}

// Pass 1: histogram of top-16 bits of ordered score (only s >= 0.5)
__global__ void k_hist1(const float* __restrict__ score, const float4* __restrict__ anchors,
                        unsigned* __restrict__ hist){
  int b = blockIdx.y;
  int i = blockIdx.x*blockDim.x + threadIdx.x;
  float s = masked_score(score, anchors, b, i);
  unsigned o = ord32(s);
  if (o >= 0xBF000000u)  // s >= 0.5
    atomicAdd(&hist[(size_t)b*65536u + (o>>16)], 1u);
}

__global__ void k_find1(const unsigned* __restrict__ hist, unsigned* __restrict__ meta){
  int b = blockIdx.x; int t = threadIdx.x;
  __shared__ unsigned part[256];
  const unsigned* h = hist + (size_t)b*65536u;
  unsigned sum = 0;
  for (int k=0;k<256;++k) sum += h[t*256+k];
  part[t]=sum; __syncthreads();
  if (t==0){
    unsigned cum=0; int tr=0;
    for (int q=255;q>=0;--q){ if (cum + part[q] >= TOPK){ tr=q; break;} cum += part[q]; }
    unsigned b1 = tr*256; unsigned cA = cum;
    for (int bin=tr*256+255; bin>=tr*256; --bin){
      unsigned hh = h[bin];
      if (cA + hh >= TOPK){ b1 = (unsigned)bin; break; }
      cA += hh;
    }
    meta[b*8+0]=b1; meta[b*8+1]=cA;
  }
}

__global__ void k_hist2(const float* __restrict__ score, const float4* __restrict__ anchors,
                        const unsigned* __restrict__ meta, unsigned* __restrict__ hist){
  int b = blockIdx.y;
  int i = blockIdx.x*blockDim.x + threadIdx.x;
  float s = masked_score(score, anchors, b, i);
  unsigned o = ord32(s);
  unsigned b1 = meta[b*8+0];
  if ((o>>16) == b1)
    atomicAdd(&hist[(size_t)b*65536u + (o & 0xFFFFu)], 1u);
}

__global__ void k_find2(const unsigned* __restrict__ hist, unsigned* __restrict__ meta){
  int b = blockIdx.x; int t = threadIdx.x;
  __shared__ unsigned part[256];
  const unsigned* h = hist + (size_t)b*65536u;
  unsigned sum=0;
  for (int k=0;k<256;++k) sum += h[t*256+k];
  part[t]=sum; __syncthreads();
  if (t==0){
    unsigned cum = meta[b*8+1];
    int tr=0;
    for (int q=255;q>=0;--q){ if (cum+part[q] >= TOPK){tr=q;break;} cum+=part[q]; }
    unsigned b2 = tr*256;
    for (int bin=tr*256+255; bin>=tr*256; --bin){
      unsigned hh=h[bin];
      if (cum+hh >= TOPK){ b2=(unsigned)bin; break; }
      cum+=hh;
    }
    meta[b*8+2] = (meta[b*8+0]<<16) | b2;  // exact 32-bit ordered-score threshold
  }
}

__global__ void k_compact(const float* __restrict__ score, const float4* __restrict__ anchors,
                          unsigned* __restrict__ meta,
                          unsigned long long* __restrict__ cand, unsigned* __restrict__ candEq){
  int b = blockIdx.y;
  int i = blockIdx.x*blockDim.x + threadIdx.x;
  float s = masked_score(score, anchors, b, i);
  unsigned o = ord32(s);
  unsigned T = meta[b*8+2];
  if (o > T){
    unsigned pos = atomicAdd(&meta[b*8+3], 1u);
    if (pos < SORTN) cand[(size_t)b*SORTN + pos] = (((unsigned long long)(~o)) << 32) | (unsigned)i;
  } else if (o == T){
    unsigned pos = atomicAdd(&meta[b*8+4], 1u);
    if (pos < SORTN) candEq[(size_t)b*SORTN + pos] = (unsigned)i;
  }
}

// Bitonic-sort candidates (pad to 8192), emit first 5000 keys (stable top-k order)
__global__ void __launch_bounds__(1024) k_sort(const unsigned* __restrict__ meta,
                       const unsigned long long* __restrict__ cand,
                       const unsigned* __restrict__ candEq,
                       unsigned long long* __restrict__ sorted){
  __shared__ unsigned long long keys[SORTN];
  int b = blockIdx.x; int t = threadIdx.x;
  unsigned cntA = meta[b*8+3];
  unsigned cntEq = meta[b*8+4];
  if (cntA > (unsigned)SORTN) cntA = SORTN;
  if (cntEq > (unsigned)SORTN - cntA) cntEq = SORTN - cntA;
  unsigned tot = cntA + cntEq;
  unsigned T = meta[b*8+2];
  unsigned long long eqHi = ((unsigned long long)(~T)) << 32;
  for (unsigned j=t; j<SORTN; j+=1024u){
    unsigned long long k;
    if (j < cntA) k = cand[(size_t)b*SORTN + j];
    else if (j < tot) k = eqHi | candEq[(size_t)b*SORTN + (j - cntA)];
    else k = ~0ull;
    keys[j]=k;
  }
  __syncthreads();
  for (unsigned k=2;k<=SORTN;k<<=1){
    for (unsigned j=k>>1;j>0;j>>=1){
      for (unsigned i=t;i<SORTN;i+=1024u){
        unsigned l = i ^ j;
        if (l > i){
          unsigned long long a = keys[i], c = keys[l];
          bool up = ((i & k) == 0u);
          if ((a > c) == up){ keys[i]=c; keys[l]=a; }
        }
      }
      __syncthreads();
    }
  }
  for (unsigned j=t;j<TOPK;j+=1024u) sorted[(size_t)b*TOPK + j] = keys[j];
}

// Sequential soft-NMS: 512 threads/block, one block per batch.
// Per-thread state (10 elems: box/area/score) in REGISTERS (static-indexed via
// full unroll). Fused IoU-update + argmax in one pass. Conservative sync:
// single-buffer partials, TWO barriers per iteration (write->barrier->read,
// then barrier before next write). bx4 in LDS only for the best-box broadcast.
__global__ void __launch_bounds__(NMS_T) k_nms(const unsigned long long* __restrict__ sorted,
                      const float4* __restrict__ anchors, const float4* __restrict__ regress,
                      float* __restrict__ out){
  __shared__ float4 bx4[TOPK];
  __shared__ unsigned long long pk[8];
  int b = blockIdx.x; int t = threadIdx.x;
  float4 bbx[NMS_K]; float sar[NMS_K]; float sco[NMS_K];
  #pragma unroll
  for (int k=0;k<NMS_K;++k){
    int j = t + k*NMS_T;
    if (j < TOPK){
      unsigned long long key = sorted[(size_t)b*TOPK + j];
      unsigned o = ~(unsigned)(key>>32);
      unsigned idx = (unsigned)key;
      float s = unord32(o);
      float4 a = anchors[idx];
      float4 d = regress[(size_t)b*N_ANCH + idx];
      float dx = d.x*0.1f, dy = d.y*0.1f;
      float dw = d.z*0.2f, dh = d.w*0.2f;
      dw = fminf(fmaxf(dw, -MAXR), MAXR);
      dh = fminf(fmaxf(dh, -MAXR), MAXR);
      float aw = a.z - a.x, ah = a.w - a.y;
      float cx = (a.z + a.x)*0.5f, cy = (a.w + a.y)*0.5f;
      float ncx = cx + dx*aw, ncy = cy + dy*ah;
      float nw = aw*expf(dw), nh = ah*expf(dh);
      float x1 = ncx - nw*0.5f, y1 = ncy - nh*0.5f;
      float x2 = ncx + nw*0.5f, y2 = ncy + nh*0.5f;
      x1 = fminf(fmaxf(x1,0.f),1.f); y1 = fminf(fmaxf(y1,0.f),1.f);
      x2 = fminf(fmaxf(x2,0.f),1.f); y2 = fminf(fmaxf(y2,0.f),1.f);
      float4 box = make_float4(x1,y1,x2,y2);
      bbx[k] = box; bx4[j] = box;
      sar[k] = (x2-x1)*(y2-y1);
      sco[k] = s;
    } else {
      bbx[k] = make_float4(0.f,0.f,0.f,0.f);
      sar[k] = 0.f;
      sco[k] = -INFINITY;
    }
  }
  __syncthreads();
  int lane = t & 63, wid = t >> 6;
  int prevBest = -1;
  float4 bb = make_float4(0.f,0.f,0.f,0.f);
  float ba = 0.f;
  for (int it=0; it<PROP; ++it){
    float bs = -INFINITY; int bp = 0;
    #pragma unroll
    for (int k=0;k<NMS_K;++k){
      int j = t + k*NMS_T;
      bool inb = (k < NMS_K-1) || (j < TOPK);
      if (inb){
        if (it > 0){
          if (j == prevBest){
            sco[k] = NEGF;
          } else {
            float ltx = fmaxf(bb.x, bbx[k].x);
            float lty = fmaxf(bb.y, bbx[k].y);
            float rbx = fminf(bb.z, bbx[k].z);
            float rby = fminf(bb.w, bbx[k].w);
            float iw = fmaxf(rbx-ltx, 0.f);
            float ih = fmaxf(rby-lty, 0.f);
            float inter = iw*ih;
            float iou = inter/(ba + sar[k] - inter + 1e-12f);
            sco[k] = sco[k]*expf(-(iou*iou));
          }
        }
        if (sco[k] > bs){ bs = sco[k]; bp = j; }
      }
    }
    // key: score desc, then slot asc (== stable first-occurrence argmax)
    unsigned long long key = (((unsigned long long)ord32(bs))<<32) | (unsigned)(0xFFFFFFFFu - (unsigned)bp);
    #pragma unroll
    for (int m=1;m<64;m<<=1){
      unsigned long long k2 = __shfl_xor(key, m);
      if (k2 > key) key = k2;
    }
    if (lane==0) pk[wid] = key;
    __syncthreads();
    #pragma unroll
    for (int w=0;w<8;++w){
      unsigned long long k2 = pk[w];
      if (k2 > key) key = k2;
    }
    int p = (int)(0xFFFFFFFFu - (unsigned)key);
    prevBest = p;
    bb = bx4[p];
    ba = (bb.z-bb.x)*(bb.w-bb.y);
    if (t==0){
      float s = unord32((unsigned)(key>>32));
      float4 ob = (s > NEGF*0.5f) ? bb : make_float4(0.f,0.f,0.f,0.f);
      *(float4*)(out + ((size_t)b*PROP + it)*4) = ob;
    }
    __syncthreads();  // pk reads done before next iteration's write
  }
}

extern "C" void kernel_launch(void* const* d_in, const int* in_sizes, int n_in,
                              void* d_out, int out_size, void* d_ws, size_t ws_size,
                              hipStream_t stream){
  const float*  score   = (const float*) d_in[0];
  const float4* regress = (const float4*)d_in[1];
  const float4* anchors = (const float4*)d_in[2];
  float* out = (float*)d_out;
  char* ws = (char*)d_ws;
  // ws layout — total use: 2 MB + 1 KB. cand/candEq/sorted ALIAS the hist
  // region (hist is dead after k_find2; stream order serializes the reuse).
  unsigned* hist = (unsigned*)(ws + 0);                          // [0, 2MB)
  unsigned* meta = (unsigned*)(ws + 2097152);                    // [2MB, 2MB+256B)
  unsigned long long* cand   = (unsigned long long*)(ws + 0);    // [0, 512KB)       alias
  unsigned* candEq           = (unsigned*)(ws + 524288);         // [512KB, 768KB)   alias
  unsigned long long* sorted = (unsigned long long*)(ws + 786432); // [768KB, ~1.08MB) alias

  hipMemsetAsync(ws, 0, 2097152 + 1024, stream);  // hist + meta
  dim3 g1(N_ANCH/256, BATCH);
  k_hist1<<<g1, 256, 0, stream>>>(score, anchors, hist);
  k_find1<<<BATCH, 256, 0, stream>>>(hist, meta);
  hipMemsetAsync(hist, 0, 2097152, stream);
  k_hist2<<<g1, 256, 0, stream>>>(score, anchors, meta, hist);
  k_find2<<<BATCH, 256, 0, stream>>>(hist, meta);
  k_compact<<<g1, 256, 0, stream>>>(score, anchors, meta, cand, candEq);
  k_sort<<<BATCH, 1024, 0, stream>>>(meta, cand, candEq, sorted);
  k_nms<<<BATCH, NMS_T, 0, stream>>>(sorted, anchors, regress, out);
}